// Round 1
// baseline (2476.914 us; speedup 1.0000x reference)
//
#include <hip/hip_runtime.h>

// LSTM: B=128, S=256, I=512, H=1024, O=512.
// R9 = R8 (parked weights, fragment-major, rotating h buffers) +
//  (1) PER-WAVE publish: wave (ct,kh) owns a 16-row x 8-unit h tile whose
//      rows are whole 16B units of hA (unit 2cg+ct). Each wave gathers its
//      tile in a private LDS slice (no cross-wave barrier), fires its own 16
//      UC stores, vmcnt(0)s, and sets its OWN flag (4 flags/block).
//  (2) INCREMENTAL stores: each activation iteration completes 2 rows ->
//      their stores issue inside the loop; the final vmcnt(0) only waits the
//      tail ack. Flag lands earlier.
//  (3) PER-WAVE consumer wait (no syncthreads): wave kh needs producers
//      cg in [kh*32,+32) x 4 waves = 128 flags; one u64 UC load per lane
//      per poll. Wave starts h-loads as soon as ITS half is ready.
//  (4) scr double-buffered by t&1 -> exactly ONE __syncthreads per step
//      (cross-kh reduce), was three.
// 256 blocks x 256 thr: block = (rq = blockIdx>>6: rows rq*32..+31,
// cg = blockIdx&63: gate-cols cg*64..+63). Wave (ct = w&1, kh = w>>1).
// h: produced via UC stores (relaxed agent atomics), consumed CACHED from
// per-step rotating buffers (cold-miss-correct; one-time acquire fence).
// Sync: per-(rq,cg,wave) flags, relaxed atomics, no per-step fences.

#define B_ 128
#define S_ 256
#define I_ 512
#define H_ 1024
#define O_ 512

typedef unsigned short u16;
typedef unsigned int u32;
typedef unsigned long long u64;

typedef short v8s __attribute__((ext_vector_type(8)));
typedef float v16f __attribute__((ext_vector_type(16)));
typedef float v4f __attribute__((ext_vector_type(4)));

__device__ __forceinline__ u16 f2bf(float f) {
  u32 u = __float_as_uint(f);
  u32 r = (u + 0x7fffu + ((u >> 16) & 1u)) >> 16;   // RNE
  return (u16)r;
}
__device__ __forceinline__ u32 pack2(float a, float b) {
  return (u32)f2bf(a) | ((u32)f2bf(b) << 16);
}
__device__ __forceinline__ uint4 cvt8(const float* __restrict__ s) {
  float4 f0 = ((const float4*)s)[0];
  float4 f1 = ((const float4*)s)[1];
  uint4 o;
  o.x = pack2(f0.x, f0.y); o.y = pack2(f0.z, f0.w);
  o.z = pack2(f1.x, f1.y); o.w = pack2(f1.z, f1.w);
  return o;
}

__device__ __forceinline__ uint4 uc_ld16(const u16* p) {
  u64 lo = __hip_atomic_load((const u64*)p, __ATOMIC_RELAXED, __HIP_MEMORY_SCOPE_AGENT);
  u64 hi = __hip_atomic_load((const u64*)p + 1, __ATOMIC_RELAXED, __HIP_MEMORY_SCOPE_AGENT);
  uint4 v; v.x = (u32)lo; v.y = (u32)(lo >> 32); v.z = (u32)hi; v.w = (u32)(hi >> 32);
  return v;
}
__device__ __forceinline__ void uc_st16(u16* p, uint4 v) {
  u64 lo = (u64)v.x | ((u64)v.y << 32);
  u64 hi = (u64)v.z | ((u64)v.w << 32);
  __hip_atomic_store((u64*)p, lo, __ATOMIC_RELAXED, __HIP_MEMORY_SCOPE_AGENT);
  __hip_atomic_store((u64*)p + 1, hi, __ATOMIC_RELAXED, __HIP_MEMORY_SCOPE_AGENT);
}

// ---------------------------------------------------------------- prep ----
__global__ void lstm_prep(
    const float* __restrict__ x,
    const float* __restrict__ Whf, const float* __restrict__ Whi,
    const float* __restrict__ Whg, const float* __restrict__ Who,
    const float* __restrict__ Wxf, const float* __restrict__ Wxi,
    const float* __restrict__ Wxg, const float* __restrict__ Wxo,
    const float* __restrict__ bfp, const float* __restrict__ bip,
    const float* __restrict__ bgp, const float* __restrict__ bop,
    const float* __restrict__ Why,
    u16* __restrict__ xt, u16* __restrict__ Wc, float* __restrict__ bc,
    u16* __restrict__ WhyT, u16* __restrict__ hbuf, u32* __restrict__ barrier)
{
  const int gid = blockIdx.x * blockDim.x + threadIdx.x;
  const int gsz = gridDim.x * blockDim.x;

  if (gid < 1024) barrier[gid] = 0u;

  // xA[t][rq][w8 0..63][row 0..31] (16B units) <- x[b=rq*32+row][t][w8*8..+8]
  for (int v = gid; v < (S_ * B_ * I_ / 8); v += gsz) {
    int flat = v * 8;
    int b = flat / (S_ * I_);
    int rem = flat - b * (S_ * I_);
    int t = rem / I_;
    int i = rem - t * I_;
    size_t dst = ((size_t)(t * 4 + (b >> 5)) * 64 + (i >> 3)) * 32 + (b & 31);
    ((uint4*)xt)[dst] = cvt8(x + flat);
  }

  // WcF[w8 0..191][colG 0..4095]: w8<64 -> Wx k=w8*8 ; w8>=64 -> Wh k=(w8-64)*8
  for (int o = gid; o < 192 * 4096; o += gsz) {
    int w8 = o >> 12;
    int colG = o & 4095;
    int unit = ((colG >> 6) << 4) + (((colG >> 5) & 1) << 3) + ((colG >> 2) & 7);
    int g = colG & 3;
    const float* Whp = (g == 0) ? Whf : (g == 1) ? Whi : (g == 2) ? Whg : Who;
    const float* Wxp = (g == 0) ? Wxf : (g == 1) ? Wxi : (g == 2) ? Wxg : Wxo;
    const float* s = (w8 < 64) ? (Wxp + (size_t)unit * 512 + w8 * 8)
                               : (Whp + (size_t)unit * 1024 + (w8 - 64) * 8);
    ((uint4*)Wc)[o] = cvt8(s);
  }

  // bias (colG-indexed)
  for (int n = gid; n < 4096; n += gsz) {
    int unit = ((n >> 6) << 4) + (((n >> 5) & 1) << 3) + ((n >> 2) & 7);
    int g = n & 3;
    const float* bp = (g == 0) ? bfp : (g == 1) ? bip : (g == 2) ? bgp : bop;
    bc[n] = bp[unit];
  }

  // Why -> bf16 (row-major [o][k])
  for (int v = gid; v < (O_ * H_ / 8); v += gsz) {
    int flat = v * 8;
    *(uint4*)(WhyT + flat) = cvt8(Why + flat);
  }

  // zero hA[0] and hA[1]
  for (int v = gid; v < 2 * 16384; v += gsz) {
    uint4 z; z.x = 0; z.y = 0; z.z = 0; z.w = 0;
    ((uint4*)hbuf)[v] = z;
  }
}

// ------------------------------------------------------ persistent LSTM ----
__global__ __launch_bounds__(256, 1) void lstm_seq(
    const u16* __restrict__ xt, const u16* __restrict__ Wc,
    const float* __restrict__ bc, u16* __restrict__ hbuf,
    const u16* __restrict__ WhyT, const float* __restrict__ WhyB,
    float* __restrict__ out, u32* __restrict__ barrier, int rotFlag)
{
  __shared__ float scr[4096];   // cross-kh partial-sum exchange, x2 buffers (16 KB)
  __shared__ u16 hws[512];      // per-wave h gather tiles: [w][rowRel 0..15][unit 0..7]

  const int tid  = threadIdx.x;
  const int lane = tid & 63;
  const int w    = tid >> 6;
  const int ct   = w & 1;             // col tile (32 cols)
  const int kh   = w >> 1;            // K half
  const int rq   = blockIdx.x >> 6;   // rows rq*32..+31
  const int cg   = blockIdx.x & 63;   // gate-cols cg*64..+63
  const bool rot = (rotFlag != 0);

  const int colN  = lane & 31;
  const int kgsel = lane >> 5;
  const int colG  = cg * 64 + ct * 32 + colN;
  const int gate  = colN & 3;                 // 0=f 1=i 2=g 3=o
  const int unitL = ct * 8 + (colN >> 2);
  const float bias = bc[colG];

  const uint4* xA4  = (const uint4*)xt;
  const uint4* WcF4 = (const uint4*)Wc;
  uint4*       HA4  = (uint4*)hbuf;

  const int xaOff = rq * 2048 + kh * 1024 + lane;                 // + t*8192 + kb*64
  const int xbOff = kh * 131072 + kgsel * 4096 + colG;            // + kb*8192
  const int haOff = rq * 4096 + kh * 2048 + lane;                 // + tb + kb*64
  const int hbOff = 262144 + kh * 262144 + kgsel * 4096 + colG;   // + kb*8192

  float c[8];
#pragma unroll
  for (int i = 0; i < 8; ++i) c[i] = 0.f;

  // One-time acquire: drop stale memset-poison / pre-prep lines so cached
  // reads of rotating h buffers (and the B preload) are correct.
  __builtin_amdgcn_fence(__ATOMIC_ACQUIRE, "agent");
  __syncthreads();

  // ---- park ALL weight B-frags in registers (192 regs/lane, AV->AGPR) ----
  v8s Bx[16], Bh[32];
  {
    const uint4* bx = WcF4 + xbOff;
#pragma unroll
    for (int kb = 0; kb < 16; ++kb)
      Bx[kb] = __builtin_bit_cast(v8s, bx[(size_t)kb * 8192]);
    const uint4* bh = WcF4 + hbOff;
#pragma unroll
    for (int kb = 0; kb < 32; ++kb)
      Bh[kb] = __builtin_bit_cast(v8s, bh[(size_t)kb * 8192]);
  }

  v16f acc0, acc1;

#pragma unroll 1
  for (int t = 0; t < S_; ++t) {
    const size_t tb = rot ? (size_t)t * 16384 : (size_t)(t & 1) * 16384;
    const size_t tn = rot ? (size_t)(t + 1) * 16384 : (size_t)((t & 1) ^ 1) * 16384;

#pragma unroll
    for (int i = 0; i < 16; ++i) { acc0[i] = 0.f; acc1[i] = 0.f; }

    // ---- x-phase: burst-load 16 A-frags, then MFMA against parked Bx ----
    {
      const uint4* ax = xA4 + (size_t)t * 8192 + xaOff;
      v8s xr[16];
#pragma unroll
      for (int kb = 0; kb < 16; ++kb)
        xr[kb] = __builtin_bit_cast(v8s, ax[kb * 64]);
#pragma unroll
      for (int kb = 0; kb < 16; ++kb) {
        if (kb & 1) acc1 = __builtin_amdgcn_mfma_f32_32x32x16_bf16(xr[kb], Bx[kb], acc1, 0, 0, 0);
        else        acc0 = __builtin_amdgcn_mfma_f32_32x32x16_bf16(xr[kb], Bx[kb], acc0, 0, 0, 0);
      }
    }

    // ---- per-wave wait: this wave's K-half needs producers cg in
    // [kh*32,+32) x 4 waves = 128 flags; lane checks one u64 (2 flags). ----
    if (t > 0) {
      const u64* fb = (const u64*)(barrier + rq * 256 + kh * 128);
      u32 spins = 0;
      for (;;) {
        u64 v = __hip_atomic_load(fb + lane, __ATOMIC_RELAXED,
                                  __HIP_MEMORY_SCOPE_AGENT);
        if ((u32)v >= (u32)t && (u32)(v >> 32) >= (u32)t) break;
        __builtin_amdgcn_s_sleep(1);
        if (++spins > (1u << 22)) break;   // safety valve
      }
    }

    // ---- h-phase: burst-load 32 A-frags, MFMA against parked Bh ----
    {
      const uint4* ah = HA4 + tb + haOff;
      v8s hr[32];
      if (rot) {
#pragma unroll
        for (int kb = 0; kb < 32; ++kb)
          hr[kb] = __builtin_bit_cast(v8s, ah[kb * 64]);
      } else {
#pragma unroll
        for (int kb = 0; kb < 32; ++kb)
          hr[kb] = __builtin_bit_cast(v8s, uc_ld16((const u16*)(ah + kb * 64)));
      }
#pragma unroll
      for (int kb = 0; kb < 32; ++kb) {
        if (kb & 1) acc1 = __builtin_amdgcn_mfma_f32_32x32x16_bf16(hr[kb], Bh[kb], acc1, 0, 0, 0);
        else        acc0 = __builtin_amdgcn_mfma_f32_32x32x16_bf16(hr[kb], Bh[kb], acc0, 0, 0, 0);
      }
    }

    // ---- cross-kh reduce (double-buffered scr), ONE barrier per step ----
    float aT[16];
#pragma unroll
    for (int i = 0; i < 16; ++i) aT[i] = acc0[i] + acc1[i];
    float* scrT = scr + ((t & 1) << 11);
    {
      int h2 = 1 - kh;
#pragma unroll
      for (int i = 0; i < 8; ++i)
        scrT[ct * 1024 + h2 * 512 + i * 64 + lane] = aT[h2 * 8 + i];
    }
    __syncthreads();

    // ---- gates, state update, per-wave incremental publish ----
    const bool lastT = (t == S_ - 1);
#pragma unroll
    for (int i = 0; i < 8; ++i) {
      int r = kh * 8 + i;
      float pre = aT[r] + scrT[ct * 1024 + kh * 512 + i * 64 + lane] + bias;
      // gate 2 -> tanh (overflow-safe), others -> sigmoid
      float e = __expf((gate == 2) ? (2.f * pre) : (-pre));
      float act = (gate == 2) ? (1.f - 2.f / (e + 1.f)) : (1.f / (1.f + e));
      int qb = lane & ~3;   // quad holds f,i,g,o of one (row,unit)
      float F = __shfl(act, qb + 0, 64);
      float I = __shfl(act, qb + 1, 64);
      float G = __shfl(act, qb + 2, 64);
      float O = __shfl(act, qb + 3, 64);
      float cn = fmaf(F, c[i], I * G);
      c[i] = cn;
      float e2 = __expf(2.f * cn);
      float hv = O * (1.f - 2.f / (e2 + 1.f));
      if (gate == 0) {
        int rowL = (r & 3) + ((r >> 2) << 3) + (kgsel << 2);   // absolute 0..31
        hws[(w << 7) + ((rowL & 15) << 3) + (colN >> 2)] = f2bf(hv);
        if (lastT) {
          int grow = rq * 32 + rowL;
          int gunit = cg * 16 + unitL;
          out[65536 + grow * H_ + gunit] = hv;    // h output (fp32)
          out[196608 + grow * H_ + gunit] = cn;   // c output (fp32)
        }
      }
      // fire this iteration's 2 completed rows (lanes 0,1; kgsel = lane).
      // Same-wave LDS write->read is in-order; no barrier needed.
      if (lane < 2) {
        int R = (r & 3) + ((r >> 2) << 3) + (lane << 2);       // absolute row
        uint4 vv = *(const uint4*)(hws + (w << 7) + ((R & 15) << 3));
        uc_st16((u16*)(HA4 + tn + rq * 4096 + (size_t)(2 * cg + ct) * 32 + R), vv);
      }
    }

    // ---- per-wave flag: most store acks already in flight ----
    asm volatile("s_waitcnt vmcnt(0)" ::: "memory");
    if (lane == 0)
      __hip_atomic_store(&barrier[rq * 256 + cg * 4 + w], (u32)(t + 1),
                         __ATOMIC_RELAXED, __HIP_MEMORY_SCOPE_AGENT);
  }

  // ---- full barrier (all 1024 per-wave flags), then out = h @ Why^T + b ----
  {
    const u64* fb = (const u64*)barrier;
#pragma unroll 1
    for (int k = tid; k < 512; k += 256) {
      u32 spins = 0;
      for (;;) {
        u64 v = __hip_atomic_load(fb + k, __ATOMIC_RELAXED,
                                  __HIP_MEMORY_SCOPE_AGENT);
        if ((u32)v >= (u32)S_ && (u32)(v >> 32) >= (u32)S_) break;
        __builtin_amdgcn_s_sleep(2);
        if (++spins > (1u << 22)) break;
      }
    }
  }
  __syncthreads();

  if (blockIdx.x < 32) {
    const int wg = blockIdx.x;
    const uint4* HF = HA4 + (rot ? (size_t)S_ * 16384 : 0);
    const int l15 = lane & 15;
    const int l4 = lane >> 4;
    const int colO = (wg << 4) + l15;
    v4f o0, o1;
#pragma unroll
    for (int i = 0; i < 4; ++i) { o0[i] = 0.f; o1[i] = 0.f; }
#pragma unroll 4
    for (int kc = 0; kc < 32; ++kc) {
      v8s bfrag = *(const v8s*)(WhyT + (size_t)colO * H_ + kc * 32 + (l4 << 3));
      size_t i0 = (size_t)w * 4096 + kc * 128 + l4 * 32 + l15;
      v8s a0, a1;
      if (rot) {
        a0 = __builtin_bit_cast(v8s, HF[i0]);
        a1 = __builtin_bit_cast(v8s, HF[i0 + 16]);
      } else {
        a0 = __builtin_bit_cast(v8s, uc_ld16((const u16*)(HF + i0)));
        a1 = __builtin_bit_cast(v8s, uc_ld16((const u16*)(HF + i0 + 16)));
      }
      o0 = __builtin_amdgcn_mfma_f32_16x16x32_bf16(a0, bfrag, o0, 0, 0, 0);
      o1 = __builtin_amdgcn_mfma_f32_16x16x32_bf16(a1, bfrag, o1, 0, 0, 0);
    }
    float bO = WhyB[colO];
#pragma unroll
    for (int r2 = 0; r2 < 4; ++r2) {
      int row = (w << 5) + (l4 << 2) + r2;
      out[row * O_ + colO] = o0[r2] + bO;
      out[(row + 16) * O_ + colO] = o1[r2] + bO;
    }
  }
}

// ------------------------------------------------------------- launch ----
extern "C" void kernel_launch(void* const* d_in, const int* in_sizes, int n_in,
                              void* d_out, int out_size, void* d_ws, size_t ws_size,
                              hipStream_t stream) {
  const float* x    = (const float*)d_in[0];
  const float* Wxf  = (const float*)d_in[1];
  const float* bf_  = (const float*)d_in[2];
  const float* Whf  = (const float*)d_in[3];
  const float* Wxi  = (const float*)d_in[4];
  const float* bi_  = (const float*)d_in[5];
  const float* Whi  = (const float*)d_in[6];
  const float* Wxg  = (const float*)d_in[7];
  const float* bg_  = (const float*)d_in[8];
  const float* Whg  = (const float*)d_in[9];
  const float* Wxo  = (const float*)d_in[10];
  const float* bo_  = (const float*)d_in[11];
  const float* Who  = (const float*)d_in[12];
  const float* Why  = (const float*)d_in[13];
  const float* Whyb = (const float*)d_in[14];

  char* ws = (char*)d_ws;
  u16*   xtp  = (u16*)(ws);                    // xA: 33,554,432 B
  u16*   Wcp  = (u16*)(ws + 33554432);         // WcF: 12,582,912 B
  float* bcp  = (float*)(ws + 46137344);       //     16,384 B
  u16*   WhyT = (u16*)(ws + 46153728);         //  1,048,576 B
  u32*   barp = (u32*)(ws + 47202304);         //      4,096 B (1024 flags)
  u16*   hbuf = (u16*)(ws + 47206400);         // hA: rot 257*256KB else 512KB
  float* outp = (float*)d_out;

  const size_t need_rot = 47206400ull + 257ull * 262144ull;  // ~114.6 MB
  int rot = (ws_size >= need_rot) ? 1 : 0;

  lstm_prep<<<dim3(1024), dim3(256), 0, stream>>>(
      x, Whf, Whi, Whg, Who, Wxf, Wxi, Wxg, Wxo,
      bf_, bi_, bg_, bo_, Why, xtp, Wcp, bcp, WhyT, hbuf, barp);

  lstm_seq<<<dim3(256), dim3(256), 0, stream>>>(
      xtp, Wcp, bcp, hbuf, WhyT, Whyb, outp, barp, rot);
}

// Round 2
// 2362.440 us; speedup vs baseline: 1.0485x; 1.0485x over previous
//
#include <hip/hip_runtime.h>

// LSTM: B=128, S=256, I=512, H=1024, O=512.
// R10 = R8 (parked weights, fragment-major, rotating h buffers, coalesced
// publish) + surgical chain cuts, with R9's write-amplification bug fixed:
//  (1) PER-WAVE publish as ONE contiguous 256B burst: wave (ct,kh) owns dest
//      unit 2cg+ct, rows kh*16..+16 -> single exec-masked store (lanes 0..15
//      x 16B). Full 32B sectors -> no write amplification (R9 regression was
//      2-row scattered stores -> WRITE_SIZE 2x). Each wave vmcnt(0)s its own
//      stores -> 4 parallel acks; pre-publish __syncthreads removed (wave
//      reads only its own LDS hws slice; same-wave LDS order suffices).
//  (2) Flag stays PER-BLOCK (one flag store, one poll word pair per cg):
//      LDS rendezvous counter (monotonic pubcnt, +1 per wave per step) gates
//      wave0's flag store. LDS poll ~200cy, off the fabric.
//  (3) PER-WAVE kh-half wait, barrier-free: wave kh polls the 32 producer
//      flags of its K-half (16 lanes x u64). scr double-buffered by t&1.
//      __syncthreads per step: 3 -> 1 (cross-kh reduce only).
// 256 blocks x 256 thr: block = (rq = blockIdx>>6: rows rq*32..+31,
// cg = blockIdx&63: gate-cols cg*64..+63). Wave (ct = w&1, kh = w>>1).
// h: produced via UC stores (relaxed agent atomics), consumed CACHED from
// per-step rotating buffers (cold-miss-correct; one-time acquire fence).
// Sync: per-block flags, relaxed atomics, no per-step fences.

#define B_ 128
#define S_ 256
#define I_ 512
#define H_ 1024
#define O_ 512

typedef unsigned short u16;
typedef unsigned int u32;
typedef unsigned long long u64;

typedef short v8s __attribute__((ext_vector_type(8)));
typedef float v16f __attribute__((ext_vector_type(16)));
typedef float v4f __attribute__((ext_vector_type(4)));

__device__ __forceinline__ u16 f2bf(float f) {
  u32 u = __float_as_uint(f);
  u32 r = (u + 0x7fffu + ((u >> 16) & 1u)) >> 16;   // RNE
  return (u16)r;
}
__device__ __forceinline__ u32 pack2(float a, float b) {
  return (u32)f2bf(a) | ((u32)f2bf(b) << 16);
}
__device__ __forceinline__ uint4 cvt8(const float* __restrict__ s) {
  float4 f0 = ((const float4*)s)[0];
  float4 f1 = ((const float4*)s)[1];
  uint4 o;
  o.x = pack2(f0.x, f0.y); o.y = pack2(f0.z, f0.w);
  o.z = pack2(f1.x, f1.y); o.w = pack2(f1.z, f1.w);
  return o;
}

__device__ __forceinline__ uint4 uc_ld16(const u16* p) {
  u64 lo = __hip_atomic_load((const u64*)p, __ATOMIC_RELAXED, __HIP_MEMORY_SCOPE_AGENT);
  u64 hi = __hip_atomic_load((const u64*)p + 1, __ATOMIC_RELAXED, __HIP_MEMORY_SCOPE_AGENT);
  uint4 v; v.x = (u32)lo; v.y = (u32)(lo >> 32); v.z = (u32)hi; v.w = (u32)(hi >> 32);
  return v;
}
__device__ __forceinline__ void uc_st16(u16* p, uint4 v) {
  u64 lo = (u64)v.x | ((u64)v.y << 32);
  u64 hi = (u64)v.z | ((u64)v.w << 32);
  __hip_atomic_store((u64*)p, lo, __ATOMIC_RELAXED, __HIP_MEMORY_SCOPE_AGENT);
  __hip_atomic_store((u64*)p + 1, hi, __ATOMIC_RELAXED, __HIP_MEMORY_SCOPE_AGENT);
}

// ---------------------------------------------------------------- prep ----
__global__ void lstm_prep(
    const float* __restrict__ x,
    const float* __restrict__ Whf, const float* __restrict__ Whi,
    const float* __restrict__ Whg, const float* __restrict__ Who,
    const float* __restrict__ Wxf, const float* __restrict__ Wxi,
    const float* __restrict__ Wxg, const float* __restrict__ Wxo,
    const float* __restrict__ bfp, const float* __restrict__ bip,
    const float* __restrict__ bgp, const float* __restrict__ bop,
    const float* __restrict__ Why,
    u16* __restrict__ xt, u16* __restrict__ Wc, float* __restrict__ bc,
    u16* __restrict__ WhyT, u16* __restrict__ hbuf, u32* __restrict__ barrier)
{
  const int gid = blockIdx.x * blockDim.x + threadIdx.x;
  const int gsz = gridDim.x * blockDim.x;

  if (gid < 1024) barrier[gid] = 0u;

  // xA[t][rq][w8 0..63][row 0..31] (16B units) <- x[b=rq*32+row][t][w8*8..+8]
  for (int v = gid; v < (S_ * B_ * I_ / 8); v += gsz) {
    int flat = v * 8;
    int b = flat / (S_ * I_);
    int rem = flat - b * (S_ * I_);
    int t = rem / I_;
    int i = rem - t * I_;
    size_t dst = ((size_t)(t * 4 + (b >> 5)) * 64 + (i >> 3)) * 32 + (b & 31);
    ((uint4*)xt)[dst] = cvt8(x + flat);
  }

  // WcF[w8 0..191][colG 0..4095]: w8<64 -> Wx k=w8*8 ; w8>=64 -> Wh k=(w8-64)*8
  for (int o = gid; o < 192 * 4096; o += gsz) {
    int w8 = o >> 12;
    int colG = o & 4095;
    int unit = ((colG >> 6) << 4) + (((colG >> 5) & 1) << 3) + ((colG >> 2) & 7);
    int g = colG & 3;
    const float* Whp = (g == 0) ? Whf : (g == 1) ? Whi : (g == 2) ? Whg : Who;
    const float* Wxp = (g == 0) ? Wxf : (g == 1) ? Wxi : (g == 2) ? Wxg : Wxo;
    const float* s = (w8 < 64) ? (Wxp + (size_t)unit * 512 + w8 * 8)
                               : (Whp + (size_t)unit * 1024 + (w8 - 64) * 8);
    ((uint4*)Wc)[o] = cvt8(s);
  }

  // bias (colG-indexed)
  for (int n = gid; n < 4096; n += gsz) {
    int unit = ((n >> 6) << 4) + (((n >> 5) & 1) << 3) + ((n >> 2) & 7);
    int g = n & 3;
    const float* bp = (g == 0) ? bfp : (g == 1) ? bip : (g == 2) ? bgp : bop;
    bc[n] = bp[unit];
  }

  // Why -> bf16 (row-major [o][k])
  for (int v = gid; v < (O_ * H_ / 8); v += gsz) {
    int flat = v * 8;
    *(uint4*)(WhyT + flat) = cvt8(Why + flat);
  }

  // zero hA[0] and hA[1]
  for (int v = gid; v < 2 * 16384; v += gsz) {
    uint4 z; z.x = 0; z.y = 0; z.z = 0; z.w = 0;
    ((uint4*)hbuf)[v] = z;
  }
}

// ------------------------------------------------------ persistent LSTM ----
__global__ __launch_bounds__(256, 1) void lstm_seq(
    const u16* __restrict__ xt, const u16* __restrict__ Wc,
    const float* __restrict__ bc, u16* __restrict__ hbuf,
    const u16* __restrict__ WhyT, const float* __restrict__ WhyB,
    float* __restrict__ out, u32* __restrict__ barrier, int rotFlag)
{
  __shared__ float scr[4096];   // cross-kh partial-sum exchange, x2 buffers (16 KB)
  __shared__ u16 hws[512];      // per-wave h tiles: [w][rowRel 0..15][unit 0..7]
  __shared__ u32 pubcnt;        // monotonic publish rendezvous (4 per step)

  const int tid  = threadIdx.x;
  const int lane = tid & 63;
  const int w    = tid >> 6;
  const int ct   = w & 1;             // col tile (32 cols)
  const int kh   = w >> 1;            // K half
  const int rq   = blockIdx.x >> 6;   // rows rq*32..+31
  const int cg   = blockIdx.x & 63;   // gate-cols cg*64..+63
  const bool rot = (rotFlag != 0);

  const int colN  = lane & 31;
  const int kgsel = lane >> 5;
  const int colG  = cg * 64 + ct * 32 + colN;
  const int gate  = colN & 3;                 // 0=f 1=i 2=g 3=o
  const int unitL = ct * 8 + (colN >> 2);
  const float bias = bc[colG];

  const uint4* xA4  = (const uint4*)xt;
  const uint4* WcF4 = (const uint4*)Wc;
  uint4*       HA4  = (uint4*)hbuf;

  const int xaOff = rq * 2048 + kh * 1024 + lane;                 // + t*8192 + kb*64
  const int xbOff = kh * 131072 + kgsel * 4096 + colG;            // + kb*8192
  const int haOff = rq * 4096 + kh * 2048 + lane;                 // + tb + kb*64
  const int hbOff = 262144 + kh * 262144 + kgsel * 4096 + colG;   // + kb*8192

  float c[8];
#pragma unroll
  for (int i = 0; i < 8; ++i) c[i] = 0.f;

  if (tid == 0) pubcnt = 0u;

  // One-time acquire: drop stale memset-poison / pre-prep lines so cached
  // reads of rotating h buffers (and the B preload) are correct.
  __builtin_amdgcn_fence(__ATOMIC_ACQUIRE, "agent");
  __syncthreads();

  // ---- park ALL weight B-frags in registers (192 regs/lane, AV->AGPR) ----
  v8s Bx[16], Bh[32];
  {
    const uint4* bx = WcF4 + xbOff;
#pragma unroll
    for (int kb = 0; kb < 16; ++kb)
      Bx[kb] = __builtin_bit_cast(v8s, bx[(size_t)kb * 8192]);
    const uint4* bh = WcF4 + hbOff;
#pragma unroll
    for (int kb = 0; kb < 32; ++kb)
      Bh[kb] = __builtin_bit_cast(v8s, bh[(size_t)kb * 8192]);
  }

  v16f acc0, acc1;

#pragma unroll 1
  for (int t = 0; t < S_; ++t) {
    const size_t tb = rot ? (size_t)t * 16384 : (size_t)(t & 1) * 16384;
    const size_t tn = rot ? (size_t)(t + 1) * 16384 : (size_t)((t & 1) ^ 1) * 16384;

#pragma unroll
    for (int i = 0; i < 16; ++i) { acc0[i] = 0.f; acc1[i] = 0.f; }

    // ---- x-phase: burst-load 16 A-frags, then MFMA against parked Bx ----
    {
      const uint4* ax = xA4 + (size_t)t * 8192 + xaOff;
      v8s xr[16];
#pragma unroll
      for (int kb = 0; kb < 16; ++kb)
        xr[kb] = __builtin_bit_cast(v8s, ax[kb * 64]);
#pragma unroll
      for (int kb = 0; kb < 16; ++kb) {
        if (kb & 1) acc1 = __builtin_amdgcn_mfma_f32_32x32x16_bf16(xr[kb], Bx[kb], acc1, 0, 0, 0);
        else        acc0 = __builtin_amdgcn_mfma_f32_32x32x16_bf16(xr[kb], Bx[kb], acc0, 0, 0, 0);
      }
    }

    // ---- per-wave kh-half wait (barrier-free): the 32 producers of this
    // wave's K-half are cg in [kh*32,+32) -> 16 lanes x u64 flag pairs. ----
    if (t > 0) {
      const u64* fb = (const u64*)(barrier + rq * 64 + kh * 32);
      u32 spins = 0;
      for (;;) {
        int ok = 1;
        if (lane < 16) {
          u64 v = __hip_atomic_load(fb + lane, __ATOMIC_RELAXED,
                                    __HIP_MEMORY_SCOPE_AGENT);
          ok = ((u32)v >= (u32)t) && ((u32)(v >> 32) >= (u32)t);
        }
        if (__all(ok)) break;
        __builtin_amdgcn_s_sleep(1);
        if (++spins > (1u << 22)) break;   // safety valve
      }
    }

    // ---- h-phase: burst-load 32 A-frags, MFMA against parked Bh ----
    {
      const uint4* ah = HA4 + tb + haOff;
      v8s hr[32];
      if (rot) {
#pragma unroll
        for (int kb = 0; kb < 32; ++kb)
          hr[kb] = __builtin_bit_cast(v8s, ah[kb * 64]);
      } else {
#pragma unroll
        for (int kb = 0; kb < 32; ++kb)
          hr[kb] = __builtin_bit_cast(v8s, uc_ld16((const u16*)(ah + kb * 64)));
      }
#pragma unroll
      for (int kb = 0; kb < 32; ++kb) {
        if (kb & 1) acc1 = __builtin_amdgcn_mfma_f32_32x32x16_bf16(hr[kb], Bh[kb], acc1, 0, 0, 0);
        else        acc0 = __builtin_amdgcn_mfma_f32_32x32x16_bf16(hr[kb], Bh[kb], acc0, 0, 0, 0);
      }
    }

    // ---- cross-kh reduce (double-buffered scr), ONE barrier per step ----
    float aT[16];
#pragma unroll
    for (int i = 0; i < 16; ++i) aT[i] = acc0[i] + acc1[i];
    float* scrT = scr + ((t & 1) << 11);
    {
      int h2 = 1 - kh;
#pragma unroll
      for (int i = 0; i < 8; ++i)
        scrT[ct * 1024 + h2 * 512 + i * 64 + lane] = aT[h2 * 8 + i];
    }
    __syncthreads();

    // ---- gates, state update; stage this wave's 16x8 h tile in hws ----
    const bool lastT = (t == S_ - 1);
#pragma unroll
    for (int i = 0; i < 8; ++i) {
      int r = kh * 8 + i;
      float pre = aT[r] + scrT[ct * 1024 + kh * 512 + i * 64 + lane] + bias;
      // gate 2 -> tanh (overflow-safe), others -> sigmoid
      float e = __expf((gate == 2) ? (2.f * pre) : (-pre));
      float act = (gate == 2) ? (1.f - 2.f / (e + 1.f)) : (1.f / (1.f + e));
      int qb = lane & ~3;   // quad holds f,i,g,o of one (row,unit)
      float F = __shfl(act, qb + 0, 64);
      float I = __shfl(act, qb + 1, 64);
      float G = __shfl(act, qb + 2, 64);
      float O = __shfl(act, qb + 3, 64);
      float cn = fmaf(F, c[i], I * G);
      c[i] = cn;
      float e2 = __expf(2.f * cn);
      float hv = O * (1.f - 2.f / (e2 + 1.f));
      if (gate == 0) {
        int rowL = (r & 3) + ((r >> 2) << 3) + (kgsel << 2);   // absolute 0..31
        hws[(w << 7) + ((rowL & 15) << 3) + (colN >> 2)] = f2bf(hv);
        if (lastT) {
          int grow = rq * 32 + rowL;
          int gunit = cg * 16 + unitL;
          out[65536 + grow * H_ + gunit] = hv;    // h output (fp32)
          out[196608 + grow * H_ + gunit] = cn;   // c output (fp32)
        }
      }
    }

    // ---- per-wave publish: ONE contiguous 256B burst (lanes 0..15 x 16B),
    // own vmcnt(0) (4 parallel acks), LDS rendezvous, wave0 sets flag. ----
    {
      if (lane < 16) {
        uint4 vv = *(const uint4*)(hws + (w << 7) + (lane << 3));
        uc_st16((u16*)(HA4 + tn + rq * 4096 + (size_t)(2 * cg + ct) * 32 +
                       kh * 16 + lane), vv);
      }
      asm volatile("s_waitcnt vmcnt(0)" ::: "memory");
      if (lane == 0) atomicAdd(&pubcnt, 1u);
      if (tid == 0) {
        u32 spins = 0;
        while (__hip_atomic_load(&pubcnt, __ATOMIC_RELAXED,
                                 __HIP_MEMORY_SCOPE_WORKGROUP) < 4u * (u32)(t + 1)) {
          if (++spins > (1u << 24)) break;   // safety valve
        }
        __hip_atomic_store(&barrier[rq * 64 + cg], (u32)(t + 1), __ATOMIC_RELAXED,
                           __HIP_MEMORY_SCOPE_AGENT);
      }
    }
  }

  // ---- full barrier (all 256 block flags), then out = h_final @ Why^T + b ----
  {
    u32 spins = 0;
    while (__hip_atomic_load(&barrier[tid], __ATOMIC_RELAXED,
                             __HIP_MEMORY_SCOPE_AGENT) < (u32)S_) {
      __builtin_amdgcn_s_sleep(2);
      if (++spins > (1u << 22)) break;
    }
  }
  __syncthreads();

  if (blockIdx.x < 32) {
    const int wg = blockIdx.x;
    const uint4* HF = HA4 + (rot ? (size_t)S_ * 16384 : 0);
    const int l15 = lane & 15;
    const int l4 = lane >> 4;
    const int colO = (wg << 4) + l15;
    v4f o0, o1;
#pragma unroll
    for (int i = 0; i < 4; ++i) { o0[i] = 0.f; o1[i] = 0.f; }
#pragma unroll 4
    for (int kc = 0; kc < 32; ++kc) {
      v8s bfrag = *(const v8s*)(WhyT + (size_t)colO * H_ + kc * 32 + (l4 << 3));
      size_t i0 = (size_t)w * 4096 + kc * 128 + l4 * 32 + l15;
      v8s a0, a1;
      if (rot) {
        a0 = __builtin_bit_cast(v8s, HF[i0]);
        a1 = __builtin_bit_cast(v8s, HF[i0 + 16]);
      } else {
        a0 = __builtin_bit_cast(v8s, uc_ld16((const u16*)(HF + i0)));
        a1 = __builtin_bit_cast(v8s, uc_ld16((const u16*)(HF + i0 + 16)));
      }
      o0 = __builtin_amdgcn_mfma_f32_16x16x32_bf16(a0, bfrag, o0, 0, 0, 0);
      o1 = __builtin_amdgcn_mfma_f32_16x16x32_bf16(a1, bfrag, o1, 0, 0, 0);
    }
    float bO = WhyB[colO];
#pragma unroll
    for (int r2 = 0; r2 < 4; ++r2) {
      int row = (w << 5) + (l4 << 2) + r2;
      out[row * O_ + colO] = o0[r2] + bO;
      out[(row + 16) * O_ + colO] = o1[r2] + bO;
    }
  }
}

// ------------------------------------------------------------- launch ----
extern "C" void kernel_launch(void* const* d_in, const int* in_sizes, int n_in,
                              void* d_out, int out_size, void* d_ws, size_t ws_size,
                              hipStream_t stream) {
  const float* x    = (const float*)d_in[0];
  const float* Wxf  = (const float*)d_in[1];
  const float* bf_  = (const float*)d_in[2];
  const float* Whf  = (const float*)d_in[3];
  const float* Wxi  = (const float*)d_in[4];
  const float* bi_  = (const float*)d_in[5];
  const float* Whi  = (const float*)d_in[6];
  const float* Wxg  = (const float*)d_in[7];
  const float* bg_  = (const float*)d_in[8];
  const float* Whg  = (const float*)d_in[9];
  const float* Wxo  = (const float*)d_in[10];
  const float* bo_  = (const float*)d_in[11];
  const float* Who  = (const float*)d_in[12];
  const float* Why  = (const float*)d_in[13];
  const float* Whyb = (const float*)d_in[14];

  char* ws = (char*)d_ws;
  u16*   xtp  = (u16*)(ws);                    // xA: 33,554,432 B
  u16*   Wcp  = (u16*)(ws + 33554432);         // WcF: 12,582,912 B
  float* bcp  = (float*)(ws + 46137344);       //     16,384 B
  u16*   WhyT = (u16*)(ws + 46153728);         //  1,048,576 B
  u32*   barp = (u32*)(ws + 47202304);         //      4,096 B
  u16*   hbuf = (u16*)(ws + 47206400);         // hA: rot 257*256KB else 512KB
  float* outp = (float*)d_out;

  const size_t need_rot = 47206400ull + 257ull * 262144ull;  // ~114.6 MB
  int rot = (ws_size >= need_rot) ? 1 : 0;

  lstm_prep<<<dim3(1024), dim3(256), 0, stream>>>(
      x, Whf, Whi, Whg, Who, Wxf, Wxi, Wxg, Wxo,
      bf_, bi_, bg_, bo_, Why, xtp, Wcp, bcp, WhyT, hbuf, barp);

  lstm_seq<<<dim3(256), dim3(256), 0, stream>>>(
      xtp, Wcp, bcp, hbuf, WhyT, Whyb, outp, barp, rot);
}

// Round 3
// 2063.015 us; speedup vs baseline: 1.2006x; 1.1451x over previous
//
#include <hip/hip_runtime.h>

// LSTM: B=128, S=256, I=512, H=1024, O=512.
// R11 = R8 EXACTLY (parked weights, fragment-major, wave0-solo publish so
// waves 1..3 run ahead under the store-ack RT, 3 syncs/step) + ONE change:
//  AGGREGATED FLAG: the 64 per-cg flags per rq are replaced by one monotonic
//  per-rq counter (own 256B-separated line). Producer: wave0 tid0 does a
//  single global atomicAdd(+1) after its vmcnt(0) ack. Consumer: tid0 ALONE
//  polls one u32 until >= 64*t, then __syncthreads releases the block.
//  Rationale: R8 had 64 blocks x 64 lanes spin-loading the SAME 256B flag
//  region at agent scope (L2-bypass) every ~600cy for the whole wait ->
//  slice congestion inflates poll RT and flag-detection latency. Single-word
//  single-lane poll cuts poll traffic ~64x. Semantics identical (counter
//  reaches 64t only after the last producer's ack'd publish).
// 256 blocks x 256 thr: block = (rq = blockIdx>>6: rows rq*32..+31,
// cg = blockIdx&63: gate-cols cg*64..+63). Wave (ct = w&1, kh = w>>1).
// h: produced via UC stores (relaxed agent atomics, write-through to fabric),
// consumed CACHED from per-step rotating buffers (cold-miss-correct; one-time
// acquire fence at start drops stale lines). UC-read fallback if ws small.
// Sync: per-rq aggregated counter, relaxed atomics, no per-step fences
// (R3: agent fences = whole-L2 wbl2/inv, measured disaster).

#define B_ 128
#define S_ 256
#define I_ 512
#define H_ 1024
#define O_ 512

typedef unsigned short u16;
typedef unsigned int u32;
typedef unsigned long long u64;

typedef short v8s __attribute__((ext_vector_type(8)));
typedef float v16f __attribute__((ext_vector_type(16)));
typedef float v4f __attribute__((ext_vector_type(4)));

__device__ __forceinline__ u16 f2bf(float f) {
  u32 u = __float_as_uint(f);
  u32 r = (u + 0x7fffu + ((u >> 16) & 1u)) >> 16;   // RNE
  return (u16)r;
}
__device__ __forceinline__ u32 pack2(float a, float b) {
  return (u32)f2bf(a) | ((u32)f2bf(b) << 16);
}
__device__ __forceinline__ uint4 cvt8(const float* __restrict__ s) {
  float4 f0 = ((const float4*)s)[0];
  float4 f1 = ((const float4*)s)[1];
  uint4 o;
  o.x = pack2(f0.x, f0.y); o.y = pack2(f0.z, f0.w);
  o.z = pack2(f1.x, f1.y); o.w = pack2(f1.z, f1.w);
  return o;
}

__device__ __forceinline__ uint4 uc_ld16(const u16* p) {
  u64 lo = __hip_atomic_load((const u64*)p, __ATOMIC_RELAXED, __HIP_MEMORY_SCOPE_AGENT);
  u64 hi = __hip_atomic_load((const u64*)p + 1, __ATOMIC_RELAXED, __HIP_MEMORY_SCOPE_AGENT);
  uint4 v; v.x = (u32)lo; v.y = (u32)(lo >> 32); v.z = (u32)hi; v.w = (u32)(hi >> 32);
  return v;
}
__device__ __forceinline__ void uc_st16(u16* p, uint4 v) {
  u64 lo = (u64)v.x | ((u64)v.y << 32);
  u64 hi = (u64)v.z | ((u64)v.w << 32);
  __hip_atomic_store((u64*)p, lo, __ATOMIC_RELAXED, __HIP_MEMORY_SCOPE_AGENT);
  __hip_atomic_store((u64*)p + 1, hi, __ATOMIC_RELAXED, __HIP_MEMORY_SCOPE_AGENT);
}

// ---------------------------------------------------------------- prep ----
__global__ void lstm_prep(
    const float* __restrict__ x,
    const float* __restrict__ Whf, const float* __restrict__ Whi,
    const float* __restrict__ Whg, const float* __restrict__ Who,
    const float* __restrict__ Wxf, const float* __restrict__ Wxi,
    const float* __restrict__ Wxg, const float* __restrict__ Wxo,
    const float* __restrict__ bfp, const float* __restrict__ bip,
    const float* __restrict__ bgp, const float* __restrict__ bop,
    const float* __restrict__ Why,
    u16* __restrict__ xt, u16* __restrict__ Wc, float* __restrict__ bc,
    u16* __restrict__ WhyT, u16* __restrict__ hbuf, u32* __restrict__ barrier)
{
  const int gid = blockIdx.x * blockDim.x + threadIdx.x;
  const int gsz = gridDim.x * blockDim.x;

  if (gid < 256) barrier[gid] = 0u;

  // xA[t][rq][w8 0..63][row 0..31] (16B units) <- x[b=rq*32+row][t][w8*8..+8]
  for (int v = gid; v < (S_ * B_ * I_ / 8); v += gsz) {
    int flat = v * 8;
    int b = flat / (S_ * I_);
    int rem = flat - b * (S_ * I_);
    int t = rem / I_;
    int i = rem - t * I_;
    size_t dst = ((size_t)(t * 4 + (b >> 5)) * 64 + (i >> 3)) * 32 + (b & 31);
    ((uint4*)xt)[dst] = cvt8(x + flat);
  }

  // WcF[w8 0..191][colG 0..4095]: w8<64 -> Wx k=w8*8 ; w8>=64 -> Wh k=(w8-64)*8
  for (int o = gid; o < 192 * 4096; o += gsz) {
    int w8 = o >> 12;
    int colG = o & 4095;
    int unit = ((colG >> 6) << 4) + (((colG >> 5) & 1) << 3) + ((colG >> 2) & 7);
    int g = colG & 3;
    const float* Whp = (g == 0) ? Whf : (g == 1) ? Whi : (g == 2) ? Whg : Who;
    const float* Wxp = (g == 0) ? Wxf : (g == 1) ? Wxi : (g == 2) ? Wxg : Wxo;
    const float* s = (w8 < 64) ? (Wxp + (size_t)unit * 512 + w8 * 8)
                               : (Whp + (size_t)unit * 1024 + (w8 - 64) * 8);
    ((uint4*)Wc)[o] = cvt8(s);
  }

  // bias (colG-indexed)
  for (int n = gid; n < 4096; n += gsz) {
    int unit = ((n >> 6) << 4) + (((n >> 5) & 1) << 3) + ((n >> 2) & 7);
    int g = n & 3;
    const float* bp = (g == 0) ? bfp : (g == 1) ? bip : (g == 2) ? bgp : bop;
    bc[n] = bp[unit];
  }

  // Why -> bf16 (row-major [o][k])
  for (int v = gid; v < (O_ * H_ / 8); v += gsz) {
    int flat = v * 8;
    *(uint4*)(WhyT + flat) = cvt8(Why + flat);
  }

  // zero hA[0] and hA[1]
  for (int v = gid; v < 2 * 16384; v += gsz) {
    uint4 z; z.x = 0; z.y = 0; z.z = 0; z.w = 0;
    ((uint4*)hbuf)[v] = z;
  }
}

// ------------------------------------------------------ persistent LSTM ----
__global__ __launch_bounds__(256, 1) void lstm_seq(
    const u16* __restrict__ xt, const u16* __restrict__ Wc,
    const float* __restrict__ bc, u16* __restrict__ hbuf,
    const u16* __restrict__ WhyT, const float* __restrict__ WhyB,
    float* __restrict__ out, u32* __restrict__ barrier, int rotFlag)
{
  __shared__ float scr[2048];   // cross-kh partial-sum exchange (8 KB)
  __shared__ u16 hstage[512];   // h gather tile: [row 0..31][unitL 0..15]

  const int tid  = threadIdx.x;
  const int lane = tid & 63;
  const int w    = tid >> 6;
  const int ct   = w & 1;             // col tile (32 cols)
  const int kh   = w >> 1;            // K half
  const int rq   = blockIdx.x >> 6;   // rows rq*32..+31
  const int cg   = blockIdx.x & 63;   // gate-cols cg*64..+63
  const bool rot = (rotFlag != 0);

  const int colN  = lane & 31;
  const int kgsel = lane >> 5;
  const int colG  = cg * 64 + ct * 32 + colN;
  const int gate  = colN & 3;                 // 0=f 1=i 2=g 3=o
  const int unitL = ct * 8 + (colN >> 2);
  const float bias = bc[colG];

  const uint4* xA4  = (const uint4*)xt;
  const uint4* WcF4 = (const uint4*)Wc;
  uint4*       HA4  = (uint4*)hbuf;

  const int xaOff = rq * 2048 + kh * 1024 + lane;                 // + t*8192 + kb*64
  const int xbOff = kh * 131072 + kgsel * 4096 + colG;            // + kb*8192
  const int haOff = rq * 4096 + kh * 2048 + lane;                 // + tb + kb*64
  const int hbOff = 262144 + kh * 262144 + kgsel * 4096 + colG;   // + kb*8192

  float c[8];
#pragma unroll
  for (int i = 0; i < 8; ++i) c[i] = 0.f;

  // One-time acquire: drop stale memset-poison / pre-prep lines so cached
  // reads of rotating h buffers (and the B preload) are correct.
  __builtin_amdgcn_fence(__ATOMIC_ACQUIRE, "agent");
  __syncthreads();

  // ---- park ALL weight B-frags in registers (192 regs/lane, AV->AGPR) ----
  v8s Bx[16], Bh[32];
  {
    const uint4* bx = WcF4 + xbOff;
#pragma unroll
    for (int kb = 0; kb < 16; ++kb)
      Bx[kb] = __builtin_bit_cast(v8s, bx[(size_t)kb * 8192]);
    const uint4* bh = WcF4 + hbOff;
#pragma unroll
    for (int kb = 0; kb < 32; ++kb)
      Bh[kb] = __builtin_bit_cast(v8s, bh[(size_t)kb * 8192]);
  }

  v16f acc0, acc1;

#pragma unroll 1
  for (int t = 0; t < S_; ++t) {
    const size_t tb = rot ? (size_t)t * 16384 : (size_t)(t & 1) * 16384;
    const size_t tn = rot ? (size_t)(t + 1) * 16384 : (size_t)((t & 1) ^ 1) * 16384;

#pragma unroll
    for (int i = 0; i < 16; ++i) { acc0[i] = 0.f; acc1[i] = 0.f; }

    // ---- x-phase: burst-load 16 A-frags, then MFMA against parked Bx ----
    {
      const uint4* ax = xA4 + (size_t)t * 8192 + xaOff;
      v8s xr[16];
#pragma unroll
      for (int kb = 0; kb < 16; ++kb)
        xr[kb] = __builtin_bit_cast(v8s, ax[kb * 64]);
#pragma unroll
      for (int kb = 0; kb < 16; ++kb) {
        if (kb & 1) acc1 = __builtin_amdgcn_mfma_f32_32x32x16_bf16(xr[kb], Bx[kb], acc1, 0, 0, 0);
        else        acc0 = __builtin_amdgcn_mfma_f32_32x32x16_bf16(xr[kb], Bx[kb], acc0, 0, 0, 0);
      }
    }

    // ---- rq-group wait: single-lane poll of the aggregated counter ----
    if (t > 0) {
      if (tid == 0) {
        u32 spins = 0;
        while (__hip_atomic_load(&barrier[rq * 64], __ATOMIC_RELAXED,
                                 __HIP_MEMORY_SCOPE_AGENT) < 64u * (u32)t) {
          __builtin_amdgcn_s_sleep(1);
          if (++spins > (1u << 22)) break;   // safety valve
        }
      }
      __syncthreads();
    }

    // ---- h-phase: burst-load 32 A-frags, MFMA against parked Bh ----
    {
      const uint4* ah = HA4 + tb + haOff;
      v8s hr[32];
      if (rot) {
#pragma unroll
        for (int kb = 0; kb < 32; ++kb)
          hr[kb] = __builtin_bit_cast(v8s, ah[kb * 64]);
      } else {
#pragma unroll
        for (int kb = 0; kb < 32; ++kb)
          hr[kb] = __builtin_bit_cast(v8s, uc_ld16((const u16*)(ah + kb * 64)));
      }
#pragma unroll
      for (int kb = 0; kb < 32; ++kb) {
        if (kb & 1) acc1 = __builtin_amdgcn_mfma_f32_32x32x16_bf16(hr[kb], Bh[kb], acc1, 0, 0, 0);
        else        acc0 = __builtin_amdgcn_mfma_f32_32x32x16_bf16(hr[kb], Bh[kb], acc0, 0, 0, 0);
      }
    }

    // ---- cross-kh reduce, gates, state update ----
    float aT[16];
#pragma unroll
    for (int i = 0; i < 16; ++i) aT[i] = acc0[i] + acc1[i];
    {
      int h2 = 1 - kh;
#pragma unroll
      for (int i = 0; i < 8; ++i)
        scr[ct * 1024 + h2 * 512 + i * 64 + lane] = aT[h2 * 8 + i];
    }
    __syncthreads();

    const bool lastT = (t == S_ - 1);
#pragma unroll
    for (int i = 0; i < 8; ++i) {
      int r = kh * 8 + i;
      float pre = aT[r] + scr[ct * 1024 + kh * 512 + i * 64 + lane] + bias;
      // gate 2 -> tanh (overflow-safe), others -> sigmoid
      float e = __expf((gate == 2) ? (2.f * pre) : (-pre));
      float act = (gate == 2) ? (1.f - 2.f / (e + 1.f)) : (1.f / (1.f + e));
      int qb = lane & ~3;   // quad holds f,i,g,o of one (row,unit)
      float F = __shfl(act, qb + 0, 64);
      float I = __shfl(act, qb + 1, 64);
      float G = __shfl(act, qb + 2, 64);
      float O = __shfl(act, qb + 3, 64);
      float cn = fmaf(F, c[i], I * G);
      c[i] = cn;
      float e2 = __expf(2.f * cn);
      float hv = O * (1.f - 2.f / (e2 + 1.f));
      if (gate == 0) {
        int rowL = (r & 3) + ((r >> 2) << 3) + (kgsel << 2);   // 0..31
        hstage[rowL * 16 + unitL] = f2bf(hv);
        if (lastT) {
          int grow = rq * 32 + rowL;
          int gunit = cg * 16 + unitL;
          out[65536 + grow * H_ + gunit] = hv;    // h output (fp32)
          out[196608 + grow * H_ + gunit] = cn;   // c output (fp32)
        }
      }
    }
    __syncthreads();

    // ---- publish: wave0 only (other waves run ahead to x of t+1; they
    // re-converge at the next wait's syncthreads, which also protects the
    // scr/hstage reuse ordering). Single atomicAdd replaces the flag. ----
    if (tid < 64) {
      int row = tid >> 1, u16sel = tid & 1;
      uint4 v = ((const uint4*)hstage)[tid];
      uc_st16((u16*)(HA4 + tn + rq * 4096 + (size_t)(2 * cg + u16sel) * 32 + row), v);
      asm volatile("s_waitcnt vmcnt(0)" ::: "memory");
      if (tid == 0)
        atomicAdd(&barrier[rq * 64], 1u);
    }
  }

  // ---- full barrier (4 aggregated counters), then out = h @ Why^T + b ----
  {
    if (tid < 4) {
      u32 spins = 0;
      while (__hip_atomic_load(&barrier[tid * 64], __ATOMIC_RELAXED,
                               __HIP_MEMORY_SCOPE_AGENT) < 64u * (u32)S_) {
        __builtin_amdgcn_s_sleep(2);
        if (++spins > (1u << 22)) break;
      }
    }
  }
  __syncthreads();

  if (blockIdx.x < 32) {
    const int wg = blockIdx.x;
    const uint4* HF = HA4 + (rot ? (size_t)S_ * 16384 : 0);
    const int l15 = lane & 15;
    const int l4 = lane >> 4;
    const int colO = (wg << 4) + l15;
    v4f o0, o1;
#pragma unroll
    for (int i = 0; i < 4; ++i) { o0[i] = 0.f; o1[i] = 0.f; }
#pragma unroll 4
    for (int kc = 0; kc < 32; ++kc) {
      v8s bfrag = *(const v8s*)(WhyT + (size_t)colO * H_ + kc * 32 + (l4 << 3));
      size_t i0 = (size_t)w * 4096 + kc * 128 + l4 * 32 + l15;
      v8s a0, a1;
      if (rot) {
        a0 = __builtin_bit_cast(v8s, HF[i0]);
        a1 = __builtin_bit_cast(v8s, HF[i0 + 16]);
      } else {
        a0 = __builtin_bit_cast(v8s, uc_ld16((const u16*)(HF + i0)));
        a1 = __builtin_bit_cast(v8s, uc_ld16((const u16*)(HF + i0 + 16)));
      }
      o0 = __builtin_amdgcn_mfma_f32_16x16x32_bf16(a0, bfrag, o0, 0, 0, 0);
      o1 = __builtin_amdgcn_mfma_f32_16x16x32_bf16(a1, bfrag, o1, 0, 0, 0);
    }
    float bO = WhyB[colO];
#pragma unroll
    for (int r2 = 0; r2 < 4; ++r2) {
      int row = (w << 5) + (l4 << 2) + r2;
      out[row * O_ + colO] = o0[r2] + bO;
      out[(row + 16) * O_ + colO] = o1[r2] + bO;
    }
  }
}

// ------------------------------------------------------------- launch ----
extern "C" void kernel_launch(void* const* d_in, const int* in_sizes, int n_in,
                              void* d_out, int out_size, void* d_ws, size_t ws_size,
                              hipStream_t stream) {
  const float* x    = (const float*)d_in[0];
  const float* Wxf  = (const float*)d_in[1];
  const float* bf_  = (const float*)d_in[2];
  const float* Whf  = (const float*)d_in[3];
  const float* Wxi  = (const float*)d_in[4];
  const float* bi_  = (const float*)d_in[5];
  const float* Whi  = (const float*)d_in[6];
  const float* Wxg  = (const float*)d_in[7];
  const float* bg_  = (const float*)d_in[8];
  const float* Whg  = (const float*)d_in[9];
  const float* Wxo  = (const float*)d_in[10];
  const float* bo_  = (const float*)d_in[11];
  const float* Who  = (const float*)d_in[12];
  const float* Why  = (const float*)d_in[13];
  const float* Whyb = (const float*)d_in[14];

  char* ws = (char*)d_ws;
  u16*   xtp  = (u16*)(ws);                    // xA: 33,554,432 B
  u16*   Wcp  = (u16*)(ws + 33554432);         // WcF: 12,582,912 B
  float* bcp  = (float*)(ws + 46137344);       //     16,384 B
  u16*   WhyT = (u16*)(ws + 46153728);         //  1,048,576 B
  u32*   barp = (u32*)(ws + 47202304);         //      1,024 B (4 padded counters)
  u16*   hbuf = (u16*)(ws + 47203328);         // hA: rot 257*256KB else 512KB
  float* outp = (float*)d_out;

  const size_t need_rot = 47203328ull + 257ull * 262144ull;  // ~114.6 MB
  int rot = (ws_size >= need_rot) ? 1 : 0;

  lstm_prep<<<dim3(1024), dim3(256), 0, stream>>>(
      x, Whf, Whi, Whg, Who, Wxf, Wxi, Wxg, Wxo,
      bf_, bi_, bg_, bo_, Why, xtp, Wcp, bcp, WhyT, hbuf, barp);

  lstm_seq<<<dim3(256), dim3(256), 0, stream>>>(
      xtp, Wcp, bcp, hbuf, WhyT, Whyb, outp, barp, rot);
}

// Round 5
// 2036.417 us; speedup vs baseline: 1.2163x; 1.0131x over previous
//
#include <hip/hip_runtime.h>

// LSTM: B=128, S=256, I=512, H=1024, O=512.
// R13 = R12 with the asm constraint fixed (ext_vector_type uint4 for the
// data operand; struct uint4 is "indirect" and rejected by clang).
//  COALESCED PUBLISH STORES: uc_st16 was 2 x 8B __hip_atomic_store per lane
//  (128 atomic-class fabric ops per 1KB publish; atomics don't coalesce ->
//  serialize at the coherence point; vmcnt(0) waits the whole batch).
//  Replaced by ONE plain global_store_dwordx4 with sc0 sc1 (agent-scope
//  write-through cache policy, same visibility semantics as the compiler's
//  agent-relaxed store lowering) -> 64 contiguous 16B lane-stores coalesce
//  to ~8 x 128B transactions. Publish-ack RT should shrink accordingly.
// 256 blocks x 256 thr: block = (rq = blockIdx>>6: rows rq*32..+31,
// cg = blockIdx&63: gate-cols cg*64..+63). Wave (ct = w&1, kh = w>>1).
// h: produced via write-through stores, consumed CACHED from per-step
// rotating buffers (cold-miss-correct; one-time acquire fence at start).
// Sync: per-rq aggregated counter, relaxed atomics, no per-step fences.

#define B_ 128
#define S_ 256
#define I_ 512
#define H_ 1024
#define O_ 512

typedef unsigned short u16;
typedef unsigned int u32;
typedef unsigned long long u64;

typedef short v8s __attribute__((ext_vector_type(8)));
typedef unsigned int v4u __attribute__((ext_vector_type(4)));
typedef float v16f __attribute__((ext_vector_type(16)));
typedef float v4f __attribute__((ext_vector_type(4)));

__device__ __forceinline__ u16 f2bf(float f) {
  u32 u = __float_as_uint(f);
  u32 r = (u + 0x7fffu + ((u >> 16) & 1u)) >> 16;   // RNE
  return (u16)r;
}
__device__ __forceinline__ u32 pack2(float a, float b) {
  return (u32)f2bf(a) | ((u32)f2bf(b) << 16);
}
__device__ __forceinline__ uint4 cvt8(const float* __restrict__ s) {
  float4 f0 = ((const float4*)s)[0];
  float4 f1 = ((const float4*)s)[1];
  uint4 o;
  o.x = pack2(f0.x, f0.y); o.y = pack2(f0.z, f0.w);
  o.z = pack2(f1.x, f1.y); o.w = pack2(f1.z, f1.w);
  return o;
}

__device__ __forceinline__ uint4 uc_ld16(const u16* p) {
  u64 lo = __hip_atomic_load((const u64*)p, __ATOMIC_RELAXED, __HIP_MEMORY_SCOPE_AGENT);
  u64 hi = __hip_atomic_load((const u64*)p + 1, __ATOMIC_RELAXED, __HIP_MEMORY_SCOPE_AGENT);
  uint4 v; v.x = (u32)lo; v.y = (u32)(lo >> 32); v.z = (u32)hi; v.w = (u32)(hi >> 32);
  return v;
}
// Agent-visible 16B publish store: plain dwordx4 with sc0 sc1 (write-through
// past L2 to the coherence point). Coalesces across lanes, unlike atomics.
// Ack is collected by the caller's s_waitcnt vmcnt(0).
__device__ __forceinline__ void uc_st16(u16* p, uint4 v) {
  v4u d;
  d.x = v.x; d.y = v.y; d.z = v.z; d.w = v.w;
  asm volatile("global_store_dwordx4 %0, %1, off sc0 sc1"
               :: "v"(p), "v"(d) : "memory");
}

// ---------------------------------------------------------------- prep ----
__global__ void lstm_prep(
    const float* __restrict__ x,
    const float* __restrict__ Whf, const float* __restrict__ Whi,
    const float* __restrict__ Whg, const float* __restrict__ Who,
    const float* __restrict__ Wxf, const float* __restrict__ Wxi,
    const float* __restrict__ Wxg, const float* __restrict__ Wxo,
    const float* __restrict__ bfp, const float* __restrict__ bip,
    const float* __restrict__ bgp, const float* __restrict__ bop,
    const float* __restrict__ Why,
    u16* __restrict__ xt, u16* __restrict__ Wc, float* __restrict__ bc,
    u16* __restrict__ WhyT, u16* __restrict__ hbuf, u32* __restrict__ barrier)
{
  const int gid = blockIdx.x * blockDim.x + threadIdx.x;
  const int gsz = gridDim.x * blockDim.x;

  if (gid < 256) barrier[gid] = 0u;

  // xA[t][rq][w8 0..63][row 0..31] (16B units) <- x[b=rq*32+row][t][w8*8..+8]
  for (int v = gid; v < (S_ * B_ * I_ / 8); v += gsz) {
    int flat = v * 8;
    int b = flat / (S_ * I_);
    int rem = flat - b * (S_ * I_);
    int t = rem / I_;
    int i = rem - t * I_;
    size_t dst = ((size_t)(t * 4 + (b >> 5)) * 64 + (i >> 3)) * 32 + (b & 31);
    ((uint4*)xt)[dst] = cvt8(x + flat);
  }

  // WcF[w8 0..191][colG 0..4095]: w8<64 -> Wx k=w8*8 ; w8>=64 -> Wh k=(w8-64)*8
  for (int o = gid; o < 192 * 4096; o += gsz) {
    int w8 = o >> 12;
    int colG = o & 4095;
    int unit = ((colG >> 6) << 4) + (((colG >> 5) & 1) << 3) + ((colG >> 2) & 7);
    int g = colG & 3;
    const float* Whp = (g == 0) ? Whf : (g == 1) ? Whi : (g == 2) ? Whg : Who;
    const float* Wxp = (g == 0) ? Wxf : (g == 1) ? Wxi : (g == 2) ? Wxg : Wxo;
    const float* s = (w8 < 64) ? (Wxp + (size_t)unit * 512 + w8 * 8)
                               : (Whp + (size_t)unit * 1024 + (w8 - 64) * 8);
    ((uint4*)Wc)[o] = cvt8(s);
  }

  // bias (colG-indexed)
  for (int n = gid; n < 4096; n += gsz) {
    int unit = ((n >> 6) << 4) + (((n >> 5) & 1) << 3) + ((n >> 2) & 7);
    int g = n & 3;
    const float* bp = (g == 0) ? bfp : (g == 1) ? bip : (g == 2) ? bgp : bop;
    bc[n] = bp[unit];
  }

  // Why -> bf16 (row-major [o][k])
  for (int v = gid; v < (O_ * H_ / 8); v += gsz) {
    int flat = v * 8;
    *(uint4*)(WhyT + flat) = cvt8(Why + flat);
  }

  // zero hA[0] and hA[1]
  for (int v = gid; v < 2 * 16384; v += gsz) {
    uint4 z; z.x = 0; z.y = 0; z.z = 0; z.w = 0;
    ((uint4*)hbuf)[v] = z;
  }
}

// ------------------------------------------------------ persistent LSTM ----
__global__ __launch_bounds__(256, 1) void lstm_seq(
    const u16* __restrict__ xt, const u16* __restrict__ Wc,
    const float* __restrict__ bc, u16* __restrict__ hbuf,
    const u16* __restrict__ WhyT, const float* __restrict__ WhyB,
    float* __restrict__ out, u32* __restrict__ barrier, int rotFlag)
{
  __shared__ float scr[2048];   // cross-kh partial-sum exchange (8 KB)
  __shared__ u16 hstage[512];   // h gather tile: [row 0..31][unitL 0..15]

  const int tid  = threadIdx.x;
  const int lane = tid & 63;
  const int w    = tid >> 6;
  const int ct   = w & 1;             // col tile (32 cols)
  const int kh   = w >> 1;            // K half
  const int rq   = blockIdx.x >> 6;   // rows rq*32..+31
  const int cg   = blockIdx.x & 63;   // gate-cols cg*64..+63
  const bool rot = (rotFlag != 0);

  const int colN  = lane & 31;
  const int kgsel = lane >> 5;
  const int colG  = cg * 64 + ct * 32 + colN;
  const int gate  = colN & 3;                 // 0=f 1=i 2=g 3=o
  const int unitL = ct * 8 + (colN >> 2);
  const float bias = bc[colG];

  const uint4* xA4  = (const uint4*)xt;
  const uint4* WcF4 = (const uint4*)Wc;
  uint4*       HA4  = (uint4*)hbuf;

  const int xaOff = rq * 2048 + kh * 1024 + lane;                 // + t*8192 + kb*64
  const int xbOff = kh * 131072 + kgsel * 4096 + colG;            // + kb*8192
  const int haOff = rq * 4096 + kh * 2048 + lane;                 // + tb + kb*64
  const int hbOff = 262144 + kh * 262144 + kgsel * 4096 + colG;   // + kb*8192

  float c[8];
#pragma unroll
  for (int i = 0; i < 8; ++i) c[i] = 0.f;

  // One-time acquire: drop stale memset-poison / pre-prep lines so cached
  // reads of rotating h buffers (and the B preload) are correct.
  __builtin_amdgcn_fence(__ATOMIC_ACQUIRE, "agent");
  __syncthreads();

  // ---- park ALL weight B-frags in registers (192 regs/lane, AV->AGPR) ----
  v8s Bx[16], Bh[32];
  {
    const uint4* bx = WcF4 + xbOff;
#pragma unroll
    for (int kb = 0; kb < 16; ++kb)
      Bx[kb] = __builtin_bit_cast(v8s, bx[(size_t)kb * 8192]);
    const uint4* bh = WcF4 + hbOff;
#pragma unroll
    for (int kb = 0; kb < 32; ++kb)
      Bh[kb] = __builtin_bit_cast(v8s, bh[(size_t)kb * 8192]);
  }

  v16f acc0, acc1;

#pragma unroll 1
  for (int t = 0; t < S_; ++t) {
    const size_t tb = rot ? (size_t)t * 16384 : (size_t)(t & 1) * 16384;
    const size_t tn = rot ? (size_t)(t + 1) * 16384 : (size_t)((t & 1) ^ 1) * 16384;

#pragma unroll
    for (int i = 0; i < 16; ++i) { acc0[i] = 0.f; acc1[i] = 0.f; }

    // ---- x-phase: burst-load 16 A-frags, then MFMA against parked Bx ----
    {
      const uint4* ax = xA4 + (size_t)t * 8192 + xaOff;
      v8s xr[16];
#pragma unroll
      for (int kb = 0; kb < 16; ++kb)
        xr[kb] = __builtin_bit_cast(v8s, ax[kb * 64]);
#pragma unroll
      for (int kb = 0; kb < 16; ++kb) {
        if (kb & 1) acc1 = __builtin_amdgcn_mfma_f32_32x32x16_bf16(xr[kb], Bx[kb], acc1, 0, 0, 0);
        else        acc0 = __builtin_amdgcn_mfma_f32_32x32x16_bf16(xr[kb], Bx[kb], acc0, 0, 0, 0);
      }
    }

    // ---- rq-group wait: single-lane poll of the aggregated counter ----
    if (t > 0) {
      if (tid == 0) {
        u32 spins = 0;
        while (__hip_atomic_load(&barrier[rq * 64], __ATOMIC_RELAXED,
                                 __HIP_MEMORY_SCOPE_AGENT) < 64u * (u32)t) {
          __builtin_amdgcn_s_sleep(1);
          if (++spins > (1u << 22)) break;   // safety valve
        }
      }
      __syncthreads();
    }

    // ---- h-phase: burst-load 32 A-frags, MFMA against parked Bh ----
    {
      const uint4* ah = HA4 + tb + haOff;
      v8s hr[32];
      if (rot) {
#pragma unroll
        for (int kb = 0; kb < 32; ++kb)
          hr[kb] = __builtin_bit_cast(v8s, ah[kb * 64]);
      } else {
#pragma unroll
        for (int kb = 0; kb < 32; ++kb)
          hr[kb] = __builtin_bit_cast(v8s, uc_ld16((const u16*)(ah + kb * 64)));
      }
#pragma unroll
      for (int kb = 0; kb < 32; ++kb) {
        if (kb & 1) acc1 = __builtin_amdgcn_mfma_f32_32x32x16_bf16(hr[kb], Bh[kb], acc1, 0, 0, 0);
        else        acc0 = __builtin_amdgcn_mfma_f32_32x32x16_bf16(hr[kb], Bh[kb], acc0, 0, 0, 0);
      }
    }

    // ---- cross-kh reduce, gates, state update ----
    float aT[16];
#pragma unroll
    for (int i = 0; i < 16; ++i) aT[i] = acc0[i] + acc1[i];
    {
      int h2 = 1 - kh;
#pragma unroll
      for (int i = 0; i < 8; ++i)
        scr[ct * 1024 + h2 * 512 + i * 64 + lane] = aT[h2 * 8 + i];
    }
    __syncthreads();

    const bool lastT = (t == S_ - 1);
#pragma unroll
    for (int i = 0; i < 8; ++i) {
      int r = kh * 8 + i;
      float pre = aT[r] + scr[ct * 1024 + kh * 512 + i * 64 + lane] + bias;
      // gate 2 -> tanh (overflow-safe), others -> sigmoid
      float e = __expf((gate == 2) ? (2.f * pre) : (-pre));
      float act = (gate == 2) ? (1.f - 2.f / (e + 1.f)) : (1.f / (1.f + e));
      int qb = lane & ~3;   // quad holds f,i,g,o of one (row,unit)
      float F = __shfl(act, qb + 0, 64);
      float I = __shfl(act, qb + 1, 64);
      float G = __shfl(act, qb + 2, 64);
      float O = __shfl(act, qb + 3, 64);
      float cn = fmaf(F, c[i], I * G);
      c[i] = cn;
      float e2 = __expf(2.f * cn);
      float hv = O * (1.f - 2.f / (e2 + 1.f));
      if (gate == 0) {
        int rowL = (r & 3) + ((r >> 2) << 3) + (kgsel << 2);   // 0..31
        hstage[rowL * 16 + unitL] = f2bf(hv);
        if (lastT) {
          int grow = rq * 32 + rowL;
          int gunit = cg * 16 + unitL;
          out[65536 + grow * H_ + gunit] = hv;    // h output (fp32)
          out[196608 + grow * H_ + gunit] = cn;   // c output (fp32)
        }
      }
    }
    __syncthreads();

    // ---- publish: wave0 only (other waves run ahead to x of t+1; they
    // re-converge at the next wait's syncthreads, which also protects the
    // scr/hstage reuse ordering). Single atomicAdd advances the counter. ----
    if (tid < 64) {
      int row = tid >> 1, u16sel = tid & 1;
      uint4 v = ((const uint4*)hstage)[tid];
      uc_st16((u16*)(HA4 + tn + rq * 4096 + (size_t)(2 * cg + u16sel) * 32 + row), v);
      asm volatile("s_waitcnt vmcnt(0)" ::: "memory");
      if (tid == 0)
        atomicAdd(&barrier[rq * 64], 1u);
    }
  }

  // ---- full barrier (4 aggregated counters), then out = h @ Why^T + b ----
  {
    if (tid < 4) {
      u32 spins = 0;
      while (__hip_atomic_load(&barrier[tid * 64], __ATOMIC_RELAXED,
                               __HIP_MEMORY_SCOPE_AGENT) < 64u * (u32)S_) {
        __builtin_amdgcn_s_sleep(2);
        if (++spins > (1u << 22)) break;
      }
    }
  }
  __syncthreads();

  if (blockIdx.x < 32) {
    const int wg = blockIdx.x;
    const uint4* HF = HA4 + (rot ? (size_t)S_ * 16384 : 0);
    const int l15 = lane & 15;
    const int l4 = lane >> 4;
    const int colO = (wg << 4) + l15;
    v4f o0, o1;
#pragma unroll
    for (int i = 0; i < 4; ++i) { o0[i] = 0.f; o1[i] = 0.f; }
#pragma unroll 4
    for (int kc = 0; kc < 32; ++kc) {
      v8s bfrag = *(const v8s*)(WhyT + (size_t)colO * H_ + kc * 32 + (l4 << 3));
      size_t i0 = (size_t)w * 4096 + kc * 128 + l4 * 32 + l15;
      v8s a0, a1;
      if (rot) {
        a0 = __builtin_bit_cast(v8s, HF[i0]);
        a1 = __builtin_bit_cast(v8s, HF[i0 + 16]);
      } else {
        a0 = __builtin_bit_cast(v8s, uc_ld16((const u16*)(HF + i0)));
        a1 = __builtin_bit_cast(v8s, uc_ld16((const u16*)(HF + i0 + 16)));
      }
      o0 = __builtin_amdgcn_mfma_f32_16x16x32_bf16(a0, bfrag, o0, 0, 0, 0);
      o1 = __builtin_amdgcn_mfma_f32_16x16x32_bf16(a1, bfrag, o1, 0, 0, 0);
    }
    float bO = WhyB[colO];
#pragma unroll
    for (int r2 = 0; r2 < 4; ++r2) {
      int row = (w << 5) + (l4 << 2) + r2;
      out[row * O_ + colO] = o0[r2] + bO;
      out[(row + 16) * O_ + colO] = o1[r2] + bO;
    }
  }
}

// ------------------------------------------------------------- launch ----
extern "C" void kernel_launch(void* const* d_in, const int* in_sizes, int n_in,
                              void* d_out, int out_size, void* d_ws, size_t ws_size,
                              hipStream_t stream) {
  const float* x    = (const float*)d_in[0];
  const float* Wxf  = (const float*)d_in[1];
  const float* bf_  = (const float*)d_in[2];
  const float* Whf  = (const float*)d_in[3];
  const float* Wxi  = (const float*)d_in[4];
  const float* bi_  = (const float*)d_in[5];
  const float* Whi  = (const float*)d_in[6];
  const float* Wxg  = (const float*)d_in[7];
  const float* bg_  = (const float*)d_in[8];
  const float* Whg  = (const float*)d_in[9];
  const float* Wxo  = (const float*)d_in[10];
  const float* bo_  = (const float*)d_in[11];
  const float* Who  = (const float*)d_in[12];
  const float* Why  = (const float*)d_in[13];
  const float* Whyb = (const float*)d_in[14];

  char* ws = (char*)d_ws;
  u16*   xtp  = (u16*)(ws);                    // xA: 33,554,432 B
  u16*   Wcp  = (u16*)(ws + 33554432);         // WcF: 12,582,912 B
  float* bcp  = (float*)(ws + 46137344);       //     16,384 B
  u16*   WhyT = (u16*)(ws + 46153728);         //  1,048,576 B
  u32*   barp = (u32*)(ws + 47202304);         //      1,024 B (4 padded counters)
  u16*   hbuf = (u16*)(ws + 47203328);         // hA: rot 257*256KB else 512KB
  float* outp = (float*)d_out;

  const size_t need_rot = 47203328ull + 257ull * 262144ull;  // ~114.6 MB
  int rot = (ws_size >= need_rot) ? 1 : 0;

  lstm_prep<<<dim3(1024), dim3(256), 0, stream>>>(
      x, Whf, Whi, Whg, Who, Wxf, Wxi, Wxg, Wxo,
      bf_, bi_, bg_, bo_, Why, xtp, Wcp, bcp, WhyT, hbuf, barp);

  lstm_seq<<<dim3(256), dim3(256), 0, stream>>>(
      xtp, Wcp, bcp, hbuf, WhyT, Whyb, outp, barp, rot);
}